// Round 1
// baseline (75.216 us; speedup 1.0000x reference)
//
#include <hip/hip_runtime.h>
#include <hip/hip_bf16.h>
#include <math.h>

#define BB 8
#define SS 512
#define EE 128
#define HH 16
#define DKK 8

// ---------------------------------------------------------------------------
// Kernel 1: QKV GEMM + bias + theta + quantum head (cumulative cos products)
// grid 256 blocks x 256 threads; each block handles 16 rows of x (4096 x 128)
// Outputs qh/kh/vh laid out as (B, H, S, 8) contiguous.
// ---------------------------------------------------------------------------
__global__ __launch_bounds__(256) void k_qkvq(
    const float* __restrict__ x,
    const float* __restrict__ Wq, const float* __restrict__ bq,
    const float* __restrict__ Wk, const float* __restrict__ bk,
    const float* __restrict__ Wv, const float* __restrict__ bv,
    const float* __restrict__ theta,
    float* __restrict__ qh, float* __restrict__ kh, float* __restrict__ vh)
{
    __shared__ float xs[16][128];
    __shared__ float cs[16][128];
    const int t = threadIdx.x;
    const int row0g = blockIdx.x * 16;

    // stage x tile (16x128 = 2048 floats = 512 float4)
    const float4* xv = (const float4*)(x + row0g * 128);
    float4* xsv = (float4*)&xs[0][0];
    xsv[t]       = xv[t];
    xsv[t + 256] = xv[t + 256];
    __syncthreads();

    const int col = t & 127;       // output column 0..127
    const int rh  = t >> 7;        // row half: 0 or 1 (rows rh*8 .. rh*8+7)
    const int h   = col >> 3;      // head
    const int w   = col & 7;       // wire
    const float th = theta[h * 8 + w];

    const float* Ws[3]   = {Wq, Wk, Wv};
    const float* bs[3]   = {bq, bk, bv};
    float*       outs[3] = {qh, kh, vh};

    for (int m = 0; m < 3; ++m) {
        const float* __restrict__ W = Ws[m];
        const float bias = bs[m][col];
        float acc[8];
        #pragma unroll
        for (int r = 0; r < 8; ++r) acc[r] = bias;

        #pragma unroll 2
        for (int k4 = 0; k4 < 32; ++k4) {
            const float w0 = W[(k4 * 4 + 0) * 128 + col];
            const float w1 = W[(k4 * 4 + 1) * 128 + col];
            const float w2 = W[(k4 * 4 + 2) * 128 + col];
            const float w3 = W[(k4 * 4 + 3) * 128 + col];
            #pragma unroll
            for (int r = 0; r < 8; ++r) {
                const float4 xv4 = ((const float4*)xs[rh * 8 + r])[k4];
                acc[r] += xv4.x * w0 + xv4.y * w1 + xv4.z * w2 + xv4.w * w3;
            }
        }

        // cos(angle) into LDS
        #pragma unroll
        for (int r = 0; r < 8; ++r)
            cs[rh * 8 + r][col] = cosf(acc[r] + th);
        __syncthreads();

        // quantum head: wire 0 -> prod c[1..7]; wire w>=1 -> prod c[0..w]
        #pragma unroll
        for (int r = 0; r < 8; ++r) {
            const float* c = &cs[rh * 8 + r][h * 8];
            float p;
            if (w == 0) {
                p = c[1] * c[2] * c[3] * c[4] * c[5] * c[6] * c[7];
            } else {
                p = c[0];
                for (int j = 1; j <= w; ++j) p *= c[j];
            }
            const int g  = row0g + rh * 8 + r;
            const int bb = g >> 9;       // batch
            const int s  = g & 511;      // seq pos
            outs[m][(((bb * HH) + h) * SS + s) * DKK + w] = p;
        }
        __syncthreads();
    }
}

// ---------------------------------------------------------------------------
// Kernel 2: attention per (b,h). K/V rows staged in LDS; one query row per
// thread; single-pass softmax (scores bounded by sqrt(8), no max needed).
// grid 256 blocks (2 per (b,h)) x 256 threads. Writes hid as (B,S,E).
// ---------------------------------------------------------------------------
__global__ __launch_bounds__(256) void k_attn(
    const float* __restrict__ qh, const float* __restrict__ kh,
    const float* __restrict__ vh, float* __restrict__ hid)
{
    __shared__ float4 kv[1024];  // 512 rows x 8 floats
    __shared__ float4 vv[1024];
    const int t    = threadIdx.x;
    const int bh   = blockIdx.x >> 1;           // 0..127 (= b*16 + h)
    const int qoff = (blockIdx.x & 1) * 256;

    const float4* kg = (const float4*)(kh + (size_t)bh * SS * DKK);
    const float4* vg = (const float4*)(vh + (size_t)bh * SS * DKK);
    #pragma unroll
    for (int i = 0; i < 4; ++i) {
        kv[t + 256 * i] = kg[t + 256 * i];
        vv[t + 256 * i] = vg[t + 256 * i];
    }

    const float4* qg = (const float4*)(qh + ((size_t)bh * SS + qoff + t) * DKK);
    const float4 q0 = qg[0];
    const float4 q1 = qg[1];
    __syncthreads();

    float a0=0.f,a1=0.f,a2=0.f,a3=0.f,a4=0.f,a5=0.f,a6=0.f,a7=0.f;
    float denom = 0.f;
    const float scale = 0.35355339059327373f;  // 1/sqrt(8)

    #pragma unroll 4
    for (int j = 0; j < 512; ++j) {
        const float4 k0 = kv[2 * j];
        const float4 k1 = kv[2 * j + 1];
        const float s = q0.x*k0.x + q0.y*k0.y + q0.z*k0.z + q0.w*k0.w
                      + q1.x*k1.x + q1.y*k1.y + q1.z*k1.z + q1.w*k1.w;
        const float e = __expf(s * scale);
        denom += e;
        const float4 v0 = vv[2 * j];
        const float4 v1 = vv[2 * j + 1];
        a0 += e * v0.x; a1 += e * v0.y; a2 += e * v0.z; a3 += e * v0.w;
        a4 += e * v1.x; a5 += e * v1.y; a6 += e * v1.z; a7 += e * v1.w;
    }

    const float inv = 1.f / denom;
    const int bb = bh >> 4, h = bh & 15, s = qoff + t;
    float* o = hid + ((size_t)(bb * SS + s) * EE) + h * DKK;
    float4 o0 = {a0 * inv, a1 * inv, a2 * inv, a3 * inv};
    float4 o1 = {a4 * inv, a5 * inv, a6 * inv, a7 * inv};
    ((float4*)o)[0] = o0;
    ((float4*)o)[1] = o1;
}

// ---------------------------------------------------------------------------
// Kernel 3: output projection hid(4096x128) @ Wo(128x128) + bo
// grid 256 blocks x 256 threads; 16 rows per block.
// ---------------------------------------------------------------------------
__global__ __launch_bounds__(256) void k_out(
    const float* __restrict__ hid, const float* __restrict__ Wo,
    const float* __restrict__ bo, float* __restrict__ out)
{
    __shared__ float hs[16][128];
    const int t = threadIdx.x;
    const int row0 = blockIdx.x * 16;

    const float4* hv = (const float4*)(hid + row0 * 128);
    float4* hsv = (float4*)&hs[0][0];
    hsv[t]       = hv[t];
    hsv[t + 256] = hv[t + 256];
    __syncthreads();

    const int col = t & 127;
    const int rh  = t >> 7;
    const float bias = bo[col];
    float acc[8];
    #pragma unroll
    for (int r = 0; r < 8; ++r) acc[r] = bias;

    #pragma unroll 2
    for (int k4 = 0; k4 < 32; ++k4) {
        const float w0 = Wo[(k4 * 4 + 0) * 128 + col];
        const float w1 = Wo[(k4 * 4 + 1) * 128 + col];
        const float w2 = Wo[(k4 * 4 + 2) * 128 + col];
        const float w3 = Wo[(k4 * 4 + 3) * 128 + col];
        #pragma unroll
        for (int r = 0; r < 8; ++r) {
            const float4 hv4 = ((const float4*)hs[rh * 8 + r])[k4];
            acc[r] += hv4.x * w0 + hv4.y * w1 + hv4.z * w2 + hv4.w * w3;
        }
    }

    #pragma unroll
    for (int r = 0; r < 8; ++r)
        out[(size_t)(row0 + rh * 8 + r) * EE + col] = acc[r];
}

// ---------------------------------------------------------------------------
extern "C" void kernel_launch(void* const* d_in, const int* in_sizes, int n_in,
                              void* d_out, int out_size, void* d_ws, size_t ws_size,
                              hipStream_t stream)
{
    const float* x     = (const float*)d_in[0];
    const float* Wq    = (const float*)d_in[1];
    const float* bq    = (const float*)d_in[2];
    const float* Wk    = (const float*)d_in[3];
    const float* bk    = (const float*)d_in[4];
    const float* Wv    = (const float*)d_in[5];
    const float* bv    = (const float*)d_in[6];
    const float* Wo    = (const float*)d_in[7];
    const float* bo    = (const float*)d_in[8];
    const float* theta = (const float*)d_in[9];
    float* out = (float*)d_out;

    float* ws  = (float*)d_ws;
    float* qh  = ws;                       // B*H*S*8 = 524288 floats
    float* kh  = ws + 524288;
    float* vh  = ws + 1048576;
    float* hid = ws + 1572864;             // B*S*E   = 524288 floats

    k_qkvq<<<256, 256, 0, stream>>>(x, Wq, bq, Wk, bk, Wv, bv, theta, qh, kh, vh);
    k_attn<<<256, 256, 0, stream>>>(qh, kh, vh, hid);
    k_out <<<256, 256, 0, stream>>>(hid, Wo, bo, out);
}

// Round 2
// 55.982 us; speedup vs baseline: 1.3436x; 1.3436x over previous
//
#include <hip/hip_runtime.h>
#include <hip/hip_bf16.h>
#include <math.h>

#define BB 8
#define SS 512
#define EE 128
#define HH 16
#define DKK 8

// ---------------------------------------------------------------------------
// Quantum head epilogue: given c = cos(angle) held by the 8 lanes of a head
// group (lane w = wire w), return the PauliZ expectation for wire w:
//   w==0 : c1*c2*...*c7
//   w>=1 : c0*c1*...*cw
// via an 8-lane Hillis-Steele inclusive product scan (no LDS, no barrier).
// ---------------------------------------------------------------------------
__device__ __forceinline__ float quantum_prod(float c, int w)
{
    float cp = (w == 0) ? 1.0f : c;   // exclude wire0 from the scan
    float p = cp;
    float u = __shfl_up(p, 1, 8); p = (w >= 1) ? p * u : p;
    u       = __shfl_up(p, 2, 8); p = (w >= 2) ? p * u : p;
    u       = __shfl_up(p, 4, 8); p = (w >= 4) ? p * u : p;
    // p = c1*...*cw  (p==1 at w==0)
    const float c0   = __shfl(c, 0, 8);  // segment lane 0
    const float full = __shfl(p, 7, 8);  // c1*...*c7
    return (w == 0) ? full : c0 * p;
}

// ---------------------------------------------------------------------------
// Kernel 1: QKV GEMM + bias + theta + quantum head.
// grid (512, 3): blockIdx.x = 8-row tile, blockIdx.y = matrix (q/k/v).
// block 256: col = t&127, rh = t>>7 selects 4 rows. x rows are read through
// wave-uniform pointers (scalar loads); W columns are coalesced vector loads.
// Output layout (B, H, S, 8).
// ---------------------------------------------------------------------------
__global__ __launch_bounds__(256) void k_qkvq(
    const float* __restrict__ x,
    const float* __restrict__ Wq, const float* __restrict__ bq,
    const float* __restrict__ Wk, const float* __restrict__ bk,
    const float* __restrict__ Wv, const float* __restrict__ bv,
    const float* __restrict__ theta,
    float* __restrict__ qh, float* __restrict__ kh, float* __restrict__ vh)
{
    const int t   = threadIdx.x;
    const int col = t & 127;
    const int rh  = t >> 7;
    const int rhu = __builtin_amdgcn_readfirstlane(rh);
    const int m   = blockIdx.y;
    const int row0 = blockIdx.x * 8 + rhu * 4;

    const float* __restrict__ W  = (m == 0) ? Wq : (m == 1) ? Wk : Wv;
    const float* __restrict__ bb = (m == 0) ? bq : (m == 1) ? bk : bv;
    float* __restrict__ outp     = (m == 0) ? qh : (m == 1) ? kh : vh;

    const float4* xr0 = (const float4*)(x + (size_t)(row0 + 0) * 128);
    const float4* xr1 = (const float4*)(x + (size_t)(row0 + 1) * 128);
    const float4* xr2 = (const float4*)(x + (size_t)(row0 + 2) * 128);
    const float4* xr3 = (const float4*)(x + (size_t)(row0 + 3) * 128);

    const float bias = bb[col];
    float acc0 = bias, acc1 = bias, acc2 = bias, acc3 = bias;

    #pragma unroll 4
    for (int k4 = 0; k4 < 32; ++k4) {
        const float w0 = W[(k4 * 4 + 0) * 128 + col];
        const float w1 = W[(k4 * 4 + 1) * 128 + col];
        const float w2 = W[(k4 * 4 + 2) * 128 + col];
        const float w3 = W[(k4 * 4 + 3) * 128 + col];
        const float4 xa = xr0[k4];
        const float4 xb = xr1[k4];
        const float4 xc = xr2[k4];
        const float4 xd = xr3[k4];
        acc0 += xa.x * w0 + xa.y * w1 + xa.z * w2 + xa.w * w3;
        acc1 += xb.x * w0 + xb.y * w1 + xb.z * w2 + xb.w * w3;
        acc2 += xc.x * w0 + xc.y * w1 + xc.z * w2 + xc.w * w3;
        acc3 += xd.x * w0 + xd.y * w1 + xd.z * w2 + xd.w * w3;
    }

    const float th = theta[col];     // theta is (16,8) contiguous = 128 floats
    const int h = col >> 3;
    const int w = col & 7;

    float acc[4] = {acc0, acc1, acc2, acc3};
    #pragma unroll
    for (int r = 0; r < 4; ++r) {
        const float c = __cosf(acc[r] + th);
        const float res = quantum_prod(c, w);
        const int g  = row0 + r;
        const int b_ = g >> 9;
        const int s  = g & 511;
        outp[(size_t)b_ * 65536 + (size_t)h * 4096 + s * 8 + w] = res;
    }
}

// ---------------------------------------------------------------------------
// Kernel 2: attention. grid 1024 = (bh 0..127) x (q-chunk 0..7 of 64 rows).
// block 256 = 4 waves; wave wv handles j in [wv*128, wv*128+128) for all 64
// q rows (lane = q row). K/V rows are wave-uniform -> scalar loads; no LDS
// staging. Partials (8 accs + denom) combined across waves through LDS.
// Single-pass softmax: |score*scale| <= sqrt(8), no max subtraction needed.
// ---------------------------------------------------------------------------
__global__ __launch_bounds__(256) void k_attn(
    const float* __restrict__ qh, const float* __restrict__ kh,
    const float* __restrict__ vh, float* __restrict__ hid)
{
    __shared__ float cmb[4][64][13];
    const int t   = threadIdx.x;
    const int L   = t & 63;
    const int wv  = t >> 6;
    const int wvu = __builtin_amdgcn_readfirstlane(wv);
    const int bh  = blockIdx.x >> 3;
    const int q0  = (blockIdx.x & 7) * 64;

    const float4* qp = (const float4*)(qh + ((size_t)bh * 512 + q0 + L) * 8);
    const float4 qa = qp[0];
    const float4 qb = qp[1];

    const float4* kb = (const float4*)(kh + (size_t)bh * 4096) + (size_t)wvu * 256;
    const float4* vb = (const float4*)(vh + (size_t)bh * 4096) + (size_t)wvu * 256;

    float a0=0.f,a1=0.f,a2=0.f,a3=0.f,a4=0.f,a5=0.f,a6=0.f,a7=0.f;
    float den = 0.f;
    const float scale = 0.35355339059327373f;  // 1/sqrt(8)

    #pragma unroll 4
    for (int j = 0; j < 128; ++j) {
        const float4 k0 = kb[2 * j];
        const float4 k1 = kb[2 * j + 1];
        const float s = qa.x*k0.x + qa.y*k0.y + qa.z*k0.z + qa.w*k0.w
                      + qb.x*k1.x + qb.y*k1.y + qb.z*k1.z + qb.w*k1.w;
        const float e = __expf(s * scale);
        den += e;
        const float4 v0 = vb[2 * j];
        const float4 v1 = vb[2 * j + 1];
        a0 += e * v0.x; a1 += e * v0.y; a2 += e * v0.z; a3 += e * v0.w;
        a4 += e * v1.x; a5 += e * v1.y; a6 += e * v1.z; a7 += e * v1.w;
    }

    cmb[wv][L][0] = a0; cmb[wv][L][1] = a1; cmb[wv][L][2] = a2; cmb[wv][L][3] = a3;
    cmb[wv][L][4] = a4; cmb[wv][L][5] = a5; cmb[wv][L][6] = a6; cmb[wv][L][7] = a7;
    cmb[wv][L][8] = den;
    __syncthreads();

    if (t < 64) {
        float r[9];
        #pragma unroll
        for (int i = 0; i < 9; ++i)
            r[i] = cmb[0][t][i] + cmb[1][t][i] + cmb[2][t][i] + cmb[3][t][i];
        const float inv = 1.0f / r[8];
        const int b_ = bh >> 4, h = bh & 15, s = q0 + t;
        float* o = hid + ((size_t)(b_ * 512 + s)) * 128 + h * 8;
        float4 o0 = {r[0]*inv, r[1]*inv, r[2]*inv, r[3]*inv};
        float4 o1 = {r[4]*inv, r[5]*inv, r[6]*inv, r[7]*inv};
        ((float4*)o)[0] = o0;
        ((float4*)o)[1] = o1;
    }
}

// ---------------------------------------------------------------------------
// Kernel 3: output projection hid(4096x128) @ Wo(128x128) + bo.
// grid 512 blocks x 256 threads, 8 rows/block, same scalar-row pattern.
// ---------------------------------------------------------------------------
__global__ __launch_bounds__(256) void k_out(
    const float* __restrict__ hid, const float* __restrict__ Wo,
    const float* __restrict__ bo, float* __restrict__ out)
{
    const int t   = threadIdx.x;
    const int col = t & 127;
    const int rh  = t >> 7;
    const int rhu = __builtin_amdgcn_readfirstlane(rh);
    const int row0 = blockIdx.x * 8 + rhu * 4;

    const float4* h0 = (const float4*)(hid + (size_t)(row0 + 0) * 128);
    const float4* h1 = (const float4*)(hid + (size_t)(row0 + 1) * 128);
    const float4* h2 = (const float4*)(hid + (size_t)(row0 + 2) * 128);
    const float4* h3 = (const float4*)(hid + (size_t)(row0 + 3) * 128);

    const float bias = bo[col];
    float acc0 = bias, acc1 = bias, acc2 = bias, acc3 = bias;

    #pragma unroll 4
    for (int k4 = 0; k4 < 32; ++k4) {
        const float w0 = Wo[(k4 * 4 + 0) * 128 + col];
        const float w1 = Wo[(k4 * 4 + 1) * 128 + col];
        const float w2 = Wo[(k4 * 4 + 2) * 128 + col];
        const float w3 = Wo[(k4 * 4 + 3) * 128 + col];
        const float4 ha = h0[k4];
        const float4 hb = h1[k4];
        const float4 hc = h2[k4];
        const float4 hd = h3[k4];
        acc0 += ha.x * w0 + ha.y * w1 + ha.z * w2 + ha.w * w3;
        acc1 += hb.x * w0 + hb.y * w1 + hb.z * w2 + hb.w * w3;
        acc2 += hc.x * w0 + hc.y * w1 + hc.z * w2 + hc.w * w3;
        acc3 += hd.x * w0 + hd.y * w1 + hd.z * w2 + hd.w * w3;
    }

    out[(size_t)(row0 + 0) * 128 + col] = acc0;
    out[(size_t)(row0 + 1) * 128 + col] = acc1;
    out[(size_t)(row0 + 2) * 128 + col] = acc2;
    out[(size_t)(row0 + 3) * 128 + col] = acc3;
}

// ---------------------------------------------------------------------------
extern "C" void kernel_launch(void* const* d_in, const int* in_sizes, int n_in,
                              void* d_out, int out_size, void* d_ws, size_t ws_size,
                              hipStream_t stream)
{
    const float* x     = (const float*)d_in[0];
    const float* Wq    = (const float*)d_in[1];
    const float* bq    = (const float*)d_in[2];
    const float* Wk    = (const float*)d_in[3];
    const float* bk    = (const float*)d_in[4];
    const float* Wv    = (const float*)d_in[5];
    const float* bv    = (const float*)d_in[6];
    const float* Wo    = (const float*)d_in[7];
    const float* bo    = (const float*)d_in[8];
    const float* theta = (const float*)d_in[9];
    float* out = (float*)d_out;

    float* ws  = (float*)d_ws;
    float* qh  = ws;                       // B*H*S*8 = 524288 floats
    float* kh  = ws + 524288;
    float* vh  = ws + 1048576;
    float* hid = ws + 1572864;             // B*S*E   = 524288 floats

    k_qkvq<<<dim3(512, 3), 256, 0, stream>>>(x, Wq, bq, Wk, bk, Wv, bv, theta, qh, kh, vh);
    k_attn<<<1024, 256, 0, stream>>>(qh, kh, vh, hid);
    k_out <<<512, 256, 0, stream>>>(hid, Wo, bo, out);
}